// Round 9
// baseline (17.854 us; speedup 1.0000x reference)
//
#include <hip/hip_runtime.h>

// MLPKANLayer: per-(in,out) scalar MLP 1->2->2->1 (relu), summed over in.
// x:[8192,64] f32 -> out:[8192,64] f32.
//
// R8: delete the LDS x-path and the phase barriers.
//  - x[b, i0..i0+3] is wave-uniform (each wave owns an i-chunk): force
//    uniformity with readfirstlane(wv) so the compiler emits s_load_dwordx4.
//    x then arrives via the SMEM pipe (co-issues with VALU, no LDS latency
//    on the critical path, no staging barrier, and fmaf(x_s, W_v, B_v)
//    reads only 1 SGPR per VALU instr = legal).
//  - Partials in unpadded ps[wv][r][o] = 16*32*64*4 = 128 KiB static LDS
//    (the size proven working in learn_hip m201). Writes: lanes o stride-1
//    -> 2 lanes/bank = free. Reduce reads: stride 8 KiB across wv -> bank
//    o%32, 2 lanes/bank = free. ONE __syncthreads pair for the whole kernel
//    (R7 had 9 barriers).
//  - Same proven 16-wave / I_CHUNK=4 / BT=32 / grid=256 (1 block/CU) shape;
//    52 weight VGPRs/lane + pin() (harmless, blocks load-sinking).
// Theory: R7's plateau (17.1 us vs 5.1 us VALU floor) = barriers + LDS
// broadcast latency + preload + fixed launch overhead. This removes the
// first two. If >=16 us remains -> overhead/latency floor, pivot to
// algorithmic cut or declare roofline.

#define IN_SIZE  64
#define OUT_SIZE 64
#define BATCH    8192

constexpr int WAVES   = 16;   // waves per block
constexpr int I_CHUNK = 4;    // i's per wave (WAVES * I_CHUNK = 64)
constexpr int BT      = 32;   // batch rows per block (grid = 256 = 1 block/CU)

__device__ __forceinline__ void pin(float& v) {
    asm volatile("" : "+v"(v));   // keeps v live in a VGPR; blocks load-sinking
}

__device__ __forceinline__ void conn(float xv, float2 W1, float2 B1,
                                     float4 W2, float2 B2, float2 W3,
                                     float& s) {
    const float h0 = fmaxf(fmaf(xv, W1.x, B1.x), 0.f);
    const float h1 = fmaxf(fmaf(xv, W1.y, B1.y), 0.f);
    float u0 = fmaf(h1, W2.y, fmaf(h0, W2.x, B2.x));
    float u1 = fmaf(h1, W2.w, fmaf(h0, W2.z, B2.y));
    u0 = fmaxf(u0, 0.f);
    u1 = fmaxf(u1, 0.f);
    s = fmaf(u0, W3.x, s);
    s = fmaf(u1, W3.y, s);
}

__global__ __launch_bounds__(1024) void kan_kernel(
    const float* __restrict__ x,
    const float* __restrict__ w1, const float* __restrict__ b1,
    const float* __restrict__ w2, const float* __restrict__ b2,
    const float* __restrict__ w3, const float* __restrict__ b3,
    float* __restrict__ out)
{
    const int tid   = threadIdx.x;
    const int o     = tid & 63;
    // readfirstlane: wv is genuinely wave-uniform; this makes it provable so
    // x addresses scalarize to s_load.
    const int wv    = __builtin_amdgcn_readfirstlane(tid >> 6);
    const int brow0 = blockIdx.x * BT;

    __shared__ float ps[WAVES][BT][OUT_SIZE];   // 128 KiB, unpadded (see header)

    // Preload this wave's i-chunk weights into registers (coalesced per lane=o).
    const int i0 = wv * I_CHUNK;
    float2 W1[I_CHUNK], B1[I_CHUNK], B2[I_CHUNK], W3[I_CHUNK];
    float4 W2[I_CHUNK];
    float bacc = 0.f;   // this wave's share of sum_i b3[i][o]
    #pragma unroll
    for (int ic = 0; ic < I_CHUNK; ++ic) {
        const int base = (i0 + ic) * OUT_SIZE + o;
        W1[ic] = reinterpret_cast<const float2*>(w1)[base];
        B1[ic] = reinterpret_cast<const float2*>(b1)[base];
        W2[ic] = reinterpret_cast<const float4*>(w2)[base];
        B2[ic] = reinterpret_cast<const float2*>(b2)[base];
        W3[ic] = reinterpret_cast<const float2*>(w3)[base];
        bacc  += b3[base];
    }
    #pragma unroll
    for (int ic = 0; ic < I_CHUNK; ++ic) {
        pin(W1[ic].x); pin(W1[ic].y);  pin(B1[ic].x); pin(B1[ic].y);
        pin(W2[ic].x); pin(W2[ic].y);  pin(W2[ic].z); pin(W2[ic].w);
        pin(B2[ic].x); pin(B2[ic].y);  pin(W3[ic].x); pin(W3[ic].y);
    }

    // Rows: x fetched via wave-uniform (scalar) 16-B loads. No LDS, no barrier.
    const float* xrow = x + brow0 * IN_SIZE + i0;
    #pragma unroll 8
    for (int r = 0; r < BT; ++r) {
        const float4 xa = *reinterpret_cast<const float4*>(xrow + r * IN_SIZE);
        float s = bacc;
        conn(xa.x, W1[0], B1[0], W2[0], B2[0], W3[0], s);
        conn(xa.y, W1[1], B1[1], W2[1], B2[1], W3[1], s);
        conn(xa.z, W1[2], B1[2], W2[2], B2[2], W3[2], s);
        conn(xa.w, W1[3], B1[3], W2[3], B2[3], W3[3], s);
        ps[wv][r][o] = s;
    }

    __syncthreads();   // the kernel's only barrier

    // Reduce 16 wave-partials per (r,o): 2048 outputs, 1024 threads -> 2 each.
    // Sum over wv ascending = i ascending (matches reference order).
    #pragma unroll
    for (int t = tid; t < BT * OUT_SIZE; t += 1024) {
        const int r = t >> 6, oo = t & 63;
        float v = 0.f;
        #pragma unroll
        for (int w = 0; w < WAVES; ++w) v += ps[w][r][oo];
        out[brow0 * OUT_SIZE + t] = v;
    }
}

extern "C" void kernel_launch(void* const* d_in, const int* in_sizes, int n_in,
                              void* d_out, int out_size, void* d_ws, size_t ws_size,
                              hipStream_t stream) {
    const float* x  = (const float*)d_in[0];
    const float* w1 = (const float*)d_in[1];
    const float* b1 = (const float*)d_in[2];
    const float* w2 = (const float*)d_in[3];
    const float* b2 = (const float*)d_in[4];
    const float* w3 = (const float*)d_in[5];
    const float* b3 = (const float*)d_in[6];
    float* out = (float*)d_out;

    const int grid = BATCH / BT;   // 256 blocks x 1024 threads = 1 block/CU
    kan_kernel<<<grid, 1024, 0, stream>>>(x, w1, b1, w2, b2, w3, b3, out);
}